// Round 1
// baseline (230.281 us; speedup 1.0000x reference)
//
#include <hip/hip_runtime.h>

// out[k][c] = x[k][c] + P[k][c]
//   P[k][2i]   = sin(k / 10000^(2i/D))
//   P[k][2i+1] = cos(k / 10000^(2i/D))
// D = 4096 (fixed by the reference), S = in_sizes[0] / D.
//
// Memory-bound: 256 MiB total traffic, ~41 us floor at 6.3 TB/s.
// Each thread owns one float4 column-quad (2 sin/cos pairs) and strides
// down rows, so the exp2-based inv_freq is computed once per thread.

#define D_DIM 4096
#define ROW4 (D_DIM / 4)   // 1024 float4 per row
#define LOG2_N 13.287712379549449f  // log2(10000)

__global__ __launch_bounds__(256) void sinusoid_add_kernel(
    const float4* __restrict__ x, float4* __restrict__ out, int S) {
    const int tid = blockIdx.x * blockDim.x + threadIdx.x;
    const int col4 = tid & (ROW4 - 1);          // fixed per thread
    int row = tid >> 10;                        // tid / ROW4
    const int rowStride = (gridDim.x * blockDim.x) >> 10;  // threads/ROW4

    // pair indices covered by this float4: p0 = col4*2 (els c,c+1), p0+1 (c+2,c+3)
    const float s = -2.0f * LOG2_N / (float)D_DIM;
    const int p0 = col4 * 2;
    const float f0 = exp2f((float)p0 * s);        // 10000^(-2*p0/D)
    const float f1 = exp2f((float)(p0 + 1) * s);
    const float inv2pi = 0.15915494309189535f;

    for (; row < S; row += rowStride) {
        const float k = (float)row;
        // angle -> revolutions -> fract -> HW sin/cos (input in revolutions)
        float r0 = k * f0 * inv2pi;
        float r1 = k * f1 * inv2pi;
        r0 -= floorf(r0);
        r1 -= floorf(r1);
        const float s0 = __builtin_amdgcn_sinf(r0);
        const float c0 = __builtin_amdgcn_cosf(r0);
        const float s1 = __builtin_amdgcn_sinf(r1);
        const float c1 = __builtin_amdgcn_cosf(r1);

        const int i = row * ROW4 + col4;
        float4 v = x[i];
        v.x += s0;
        v.y += c0;
        v.z += s1;
        v.w += c1;
        out[i] = v;
    }
}

extern "C" void kernel_launch(void* const* d_in, const int* in_sizes, int n_in,
                              void* d_out, int out_size, void* d_ws, size_t ws_size,
                              hipStream_t stream) {
    const float* x = (const float*)d_in[0];
    float* out = (float*)d_out;
    const int S = in_sizes[0] / D_DIM;  // 8192

    // 2048 blocks x 256 threads = 524288 threads = 512 column-sweeps;
    // multiple of ROW4 so col4 stays fixed across the grid-stride loop.
    dim3 grid(2048), block(256);
    sinusoid_add_kernel<<<grid, block, 0, stream>>>(
        (const float4*)x, (float4*)out, S);
}

// Round 3
// 221.112 us; speedup vs baseline: 1.0415x; 1.0415x over previous
//
#include <hip/hip_runtime.h>

// out[k][c] = x[k][c] + P[k][c]
//   P[k][2i]   = sin(k / 10000^(2i/D))
//   P[k][2i+1] = cos(k / 10000^(2i/D))
// D = 4096 (fixed by the reference), S = in_sizes[0] / D.
//
// Memory-bound: 256 MiB total traffic, ~42 us floor at 6.3 TB/s.
// Each thread owns one float4 column-quad (2 sin/cos pairs) and strides
// down rows. inv_freq is computed once per thread; the phase advances
// incrementally (r += dr) so the loop body is load / fract / sin+cos /
// add / store with no per-iter int->float or mul.
// Non-temporal load+store: both streams are touched exactly once, so
// bypassing L2/L3 avoids cache pollution on the 256 MiB of traffic.
// NOTE: __builtin_nontemporal_* needs a native clang vector type, not
// HIP_vector_type<float,4> -- use ext_vector_type(4).

#define D_DIM 4096
#define ROW4 (D_DIM / 4)   // 1024 float4 per row
#define LOG2_N 13.287712379549449f  // log2(10000)

typedef float f32x4 __attribute__((ext_vector_type(4)));

__global__ __launch_bounds__(256) void sinusoid_add_kernel(
    const f32x4* __restrict__ x, f32x4* __restrict__ out, int S) {
    const int tid = blockIdx.x * blockDim.x + threadIdx.x;
    const int col4 = tid & (ROW4 - 1);               // fixed per thread
    const int row0 = tid >> 10;                      // tid / ROW4
    const int rowStride = (gridDim.x * blockDim.x) >> 10;  // 512

    // frequencies for the two sin/cos pairs in this float4, pre-scaled to
    // revolutions: f = 10000^(-p/(D/2)) / (2*pi)
    const float sCoef = -2.0f * LOG2_N / (float)D_DIM;
    const float inv2pi = 0.15915494309189535f;
    const int p0 = col4 * 2;
    const float f0 = exp2f((float)p0 * sCoef) * inv2pi;
    const float f1 = exp2f((float)(p0 + 1) * sCoef) * inv2pi;

    float r0 = (float)row0 * f0;
    float r1 = (float)row0 * f1;
    const float dr0 = (float)rowStride * f0;
    const float dr1 = (float)rowStride * f1;

    const f32x4* xp = x + (size_t)row0 * ROW4 + col4;
    f32x4*       op = out + (size_t)row0 * ROW4 + col4;
    const int step = rowStride * ROW4;

    for (int row = row0; row < S; row += rowStride) {
        f32x4 v = __builtin_nontemporal_load(xp);
        // revolutions -> [0,1) -> HW sin/cos (inputs in revolutions)
        const float a0 = r0 - floorf(r0);
        const float a1 = r1 - floorf(r1);
        v.x += __builtin_amdgcn_sinf(a0);
        v.y += __builtin_amdgcn_cosf(a0);
        v.z += __builtin_amdgcn_sinf(a1);
        v.w += __builtin_amdgcn_cosf(a1);
        __builtin_nontemporal_store(v, op);
        r0 += dr0;
        r1 += dr1;
        xp += step;
        op += step;
    }
}

extern "C" void kernel_launch(void* const* d_in, const int* in_sizes, int n_in,
                              void* d_out, int out_size, void* d_ws, size_t ws_size,
                              hipStream_t stream) {
    const float* x = (const float*)d_in[0];
    float* out = (float*)d_out;
    const int S = in_sizes[0] / D_DIM;  // 8192

    // 2048 blocks x 256 threads = 524288 threads = 512 column-sweeps;
    // multiple of ROW4 so col4 stays fixed across the grid-stride loop.
    // 8 blocks/CU -> full 32 waves/CU occupancy.
    dim3 grid(2048), block(256);
    sinusoid_add_kernel<<<grid, block, 0, stream>>>(
        (const f32x4*)x, (f32x4*)out, S);
}